// Round 1
// baseline (362.382 us; speedup 1.0000x reference)
//
#include <hip/hip_runtime.h>

// CTC greedy decode: B=1024, T=512, C=128, blank=C-1.
// One block per batch row, 512 threads (8 waves).
// Stage 1: argmax over C per timestep (wave-half = one timestep, float4/lane).
// Stage 2: collapse+deblank via block prefix scan, scatter into LDS, coalesced store.

constexpr int T_DIM = 512;
constexpr int C_DIM = 128;
constexpr int BLANK = C_DIM - 1;
constexpr int BLOCK = 512;

__global__ __launch_bounds__(BLOCK) void ctc_decode_kernel(
    const float* __restrict__ probs,
    const int* __restrict__ table,
    const int* __restrict__ defc_p,
    int* __restrict__ out)
{
    __shared__ int s_best[T_DIM];
    __shared__ int s_chars[T_DIM];
    __shared__ int s_table[C_DIM];
    __shared__ int s_wavesums[BLOCK / 64];

    const int b    = blockIdx.x;
    const int tid  = threadIdx.x;
    const int lane = tid & 63;
    const int wave = tid >> 6;

    if (tid < C_DIM) s_table[tid] = table[tid];
    const int defc = defc_p[0];

    const float* row = probs + (size_t)b * T_DIM * C_DIM;

    // ---- Stage 1: per-timestep argmax (first-occurrence tie-break) ----
    // Each wave: lanes 0-31 handle timestep t, lanes 32-63 handle t+1.
    // Lane reads float4 -> wave reads 1KB contiguous. 8 waves -> 16 timesteps/iter.
    const int half = lane >> 5;   // which timestep of the pair
    const int s    = lane & 31;   // position within the 32-lane half
    for (int it = 0; it < T_DIM / 16; ++it) {
        const int t = it * 16 + wave * 2 + half;
        const float4 v4 = *(const float4*)(row + (size_t)t * C_DIM + s * 4);
        float bv = v4.x; int bi = s * 4;
        if (v4.y > bv) { bv = v4.y; bi = s * 4 + 1; }
        if (v4.z > bv) { bv = v4.z; bi = s * 4 + 2; }
        if (v4.w > bv) { bv = v4.w; bi = s * 4 + 3; }
        // Butterfly reduce within each 32-lane half (xor masks <=16 never cross halves).
        #pragma unroll
        for (int m = 16; m >= 1; m >>= 1) {
            const float ov = __shfl_xor(bv, m);
            const int   oi = __shfl_xor(bi, m);
            if (ov > bv || (ov == bv && oi < bi)) { bv = ov; bi = oi; }
        }
        if (s == 0) s_best[t] = bi;
    }
    __syncthreads();

    // ---- Stage 2: valid mask + block inclusive scan ----
    const int best_t = s_best[tid];
    const int prev   = (tid > 0) ? s_best[tid - 1] : -1;
    const int valid  = (best_t != prev && best_t != BLANK) ? 1 : 0;

    int scan = valid;
    #pragma unroll
    for (int off = 1; off < 64; off <<= 1) {
        const int v = __shfl_up(scan, off);
        if (lane >= off) scan += v;
    }
    if (lane == 63) s_wavesums[wave] = scan;
    __syncthreads();
    if (tid == 0) {
        int acc = 0;
        #pragma unroll
        for (int w = 0; w < BLOCK / 64; ++w) {
            const int tmp = s_wavesums[w];
            s_wavesums[w] = acc;
            acc += tmp;
        }
    }
    __syncthreads();
    const int pos = scan + s_wavesums[wave] - 1;  // exclusive position among valid

    // ---- Scatter chars into LDS row, then coalesced store ----
    s_chars[tid] = defc;
    __syncthreads();
    if (valid) s_chars[pos] = s_table[best_t];
    __syncthreads();
    out[(size_t)b * T_DIM + tid] = s_chars[tid];
}

extern "C" void kernel_launch(void* const* d_in, const int* in_sizes, int n_in,
                              void* d_out, int out_size, void* d_ws, size_t ws_size,
                              hipStream_t stream) {
    const float* probs = (const float*)d_in[0];
    const int*   table = (const int*)d_in[1];
    const int*   defc  = (const int*)d_in[2];
    int*         out   = (int*)d_out;

    const int B = out_size / T_DIM;  // 1024
    ctc_decode_kernel<<<dim3(B), dim3(BLOCK), 0, stream>>>(probs, table, defc, out);
}